// Round 9
// baseline (207.329 us; speedup 1.0000x reference)
//
#include <hip/hip_runtime.h>
#include <hip/hip_fp16.h>
#include <math.h>

typedef __attribute__((ext_vector_type(8))) short short8;
typedef __attribute__((ext_vector_type(16))) float floatx16;
typedef __attribute__((ext_vector_type(2))) __bf16 bf16x2;

namespace {
constexpr int Bn = 8;
constexpr int Sn = 2048;
constexpr int Dn = 128;
constexpr int BQ = 128;                // queries per block (4 waves x 32)
constexpr int BK = 64;                 // keys per tile
constexpr int QTILES = Sn / BQ;        // 16
constexpr int NKB = Sn / BK;           // 32
constexpr int ROWS = Bn * Sn;          // 16384
constexpr int NSPLIT = 4;              // grid 512 blocks(256thr) = 2 blocks/CU
constexpr int NGRP = Bn * QTILES;      // 128 (b,q0) groups
constexpr float SC2 = 0.12753102063642597f;  // (1/sqrt(128)) * log2(e)
constexpr int TILE_USH = BK * Dn;      // 8192 ushorts = 16 KB tile
}

#if __has_builtin(__builtin_amdgcn_exp2f)
#define EXP2(x) __builtin_amdgcn_exp2f(x)
#else
#define EXP2(x) exp2f(x)
#endif

__device__ __forceinline__ unsigned short f2bf(float x) {
  union { float f; unsigned u; } a; a.f = x;
  unsigned r = a.u + 0x7fffu + ((a.u >> 16) & 1u);   // RNE
  return (unsigned short)(r >> 16);
}

// HW packed convert: 2 floats -> bf16x2 (v_cvt_pk_bf16_f32)
__device__ __forceinline__ unsigned pack2bf(float x, float y) {
  union { bf16x2 b; unsigned u; } c;
  c.b[0] = (__bf16)x; c.b[1] = (__bf16)y;
  return c.u;
}

__device__ __forceinline__ void gl_lds16(const void* g, void* l, int lane) {
#if __has_builtin(__builtin_amdgcn_global_load_lds)
  (void)lane;
  __builtin_amdgcn_global_load_lds((const __attribute__((address_space(1))) unsigned int*)g,
                                   (__attribute__((address_space(3))) unsigned int*)l, 16, 0, 0);
#else
  *(float4*)((char*)l + lane * 16) = *(const float4*)g;
#endif
}

// ---------------- pre-pass (1024 blocks x 256 thr, 16 keys each):
// K -> bf16 swizzled tiles [key][oct(d>>3)^(key&7)], V -> bf16 transposed tiles
// [d][oct(key>>3)^(d&7)], mask -> bias floats, and zero the split-K ticket counters.
__global__ __launch_bounds__(256)
void prep(const float* __restrict__ kg, const float* __restrict__ vg,
          const unsigned char* __restrict__ mraw,
          unsigned short* __restrict__ Kpg, unsigned short* __restrict__ Vpg,
          float* __restrict__ mb2g, int* __restrict__ cnt) {
  __shared__ __align__(16) float Vf[16 * 136];
  const int p = blockIdx.x;
  const int b = p >> 7, q = p & 127;
  const int kb = q >> 2, k16 = q & 3;
  const int t = threadIdx.x;

  if (p == 0 && t < NGRP) cnt[t] = 0;   // stream-ordered before attn_fwd

  unsigned wv = ((const unsigned int*)mraw)[t];
  int any1  = __syncthreads_or((wv & 0x0000ff00u) ? 1 : 0);
  int any23 = __syncthreads_or((wv & 0xffff0000u) ? 1 : 0);
  const int mlayout = any1 ? 1 : (any23 ? 2 : 0);
  if (p < 64) {
    int idx = p * 256 + t;
    bool ms;
    if (mlayout == 1)      ms = mraw[idx] != 0;
    else if (mlayout == 2) ms = ((const float*)mraw)[idx] != 0.0f;
    else                   ms = ((const int*)mraw)[idx] != 0;
    mb2g[idx] = ms ? -1e30f : 0.0f;
  }

  const int j  = t >> 4;
  const int o8 = t & 15;
  const size_t base = ((size_t)(b * Sn + kb * 64 + k16 * 16 + j)) * 32 + o8 * 2;
  const float4* k4 = (const float4*)kg;
  const float4* v4 = (const float4*)vg;

  {
    float4 a = k4[base], bq = k4[base + 1];
    union { unsigned u[4]; short8 s8; } pk;
    pk.u[0] = pack2bf(a.x, a.y);   pk.u[1] = pack2bf(a.z, a.w);
    pk.u[2] = pack2bf(bq.x, bq.y); pk.u[3] = pack2bf(bq.z, bq.w);
    const int jl = k16 * 16 + j;
    *(short8*)(Kpg + (size_t)(b * NKB + kb) * TILE_USH + jl * 128 + ((o8 ^ (jl & 7)) * 8)) = pk.s8;
  }
  {
    float4 a = v4[base], bq = v4[base + 1];
    *(float4*)&Vf[j * 136 + o8 * 8]     = a;
    *(float4*)&Vf[j * 136 + o8 * 8 + 4] = bq;
  }
  __syncthreads();
  {
    const int d = t >> 1, h = t & 1;
    union { unsigned u[4]; short8 s8; } pv;
    #pragma unroll
    for (int i = 0; i < 4; ++i)
      pv.u[i] = pack2bf(Vf[(h * 8 + 2 * i) * 136 + d], Vf[(h * 8 + 2 * i + 1) * 136 + d]);
    const int og = k16 * 2 + h;
    *(short8*)(Vpg + (size_t)(b * NKB + kb) * TILE_USH + d * 64 + ((og ^ (d & 7)) * 8)) = pv.s8;
  }
}

// ---------------- main flash kernel, mfma_f32_32x32x16_bf16, double-buffered K-loop,
// FUSED split-K combine: last split block of each (b,q0) group merges the 4 partials.
template<int SPLIT, bool DIRECT>
__global__ __launch_bounds__(256, 2)
void attn_fwd(const float* __restrict__ qg,
              const unsigned short* __restrict__ Kpg,
              const unsigned short* __restrict__ Vpg,
              const float* __restrict__ mb2g,
              float* __restrict__ outg, __half* __restrict__ Op,
              float* __restrict__ Mp, float* __restrict__ Lp,
              int* __restrict__ cnt) {
  __shared__ __align__(16) unsigned short Khi[2][TILE_USH];  // 32768 B
  __shared__ __align__(16) unsigned short Vt[2][TILE_USH];   // 32768 B
  __shared__ __align__(16) unsigned short Pq[4 * 2048];      // 16384 B (per-wave 32q x 64k)
  __shared__ int lastflag;
  // total 81920 B -> exactly 2 blocks/CU

  const int tid = threadIdx.x;
  const int bid = blockIdx.x;
  const int b   = bid & 7;                       // batch -> XCD swizzle
  const int q0  = ((bid >> 3) & (QTILES - 1)) * BQ;
  const int s   = bid >> 7;                      // split index (0 when SPLIT==1)
  const int kb0 = s * (NKB / SPLIT);
  const int kbN = kb0 + NKB / SPLIT;
  const int w   = tid >> 6;                      // wave 0..3
  const int L   = tid & 63;
  const int q   = L & 31;                        // query within wave
  const int h   = L >> 5;                        // k-half selector
  const int sw  = q & 7;                         // octet XOR swizzle key

  const char* ktile = (const char*)(Kpg + (size_t)b * NKB * TILE_USH);
  const char* vtile = (const char*)(Vpg + (size_t)b * NKB * TILE_USH);
  const int stagebase = w * 4096;                // wave's quarter of a 16 KB tile

  // Q B-fragments: lane holds Q[row q][d = kstep*16 + h*8 + j], hi/lo split
  short8 qh[8], ql[8];
  {
    const float* qrow = qg + (size_t)(b * Sn + q0 + w * 32 + q) * Dn;
    #pragma unroll
    for (int kstep = 0; kstep < 8; ++kstep) {
      float4 f0 = *(const float4*)(qrow + kstep * 16 + h * 8);
      float4 f1 = *(const float4*)(qrow + kstep * 16 + h * 8 + 4);
      float xs[8] = {f0.x, f0.y, f0.z, f0.w, f1.x, f1.y, f1.z, f1.w};
      #pragma unroll
      for (int j = 0; j < 8; ++j) {
        unsigned short hi = f2bf(xs[j]);
        union { unsigned u; float f; } hv; hv.u = ((unsigned)hi) << 16;
        qh[kstep][j] = (short)hi;
        ql[kstep][j] = (short)f2bf(xs[j] - hv.f);
      }
    }
  }

  float m_i = -INFINITY, l_i = 0.0f;
  floatx16 O32[4];
  #pragma unroll
  for (int dg = 0; dg < 4; ++dg)
    #pragma unroll
    for (int r = 0; r < 16; ++r) O32[dg][r] = 0.0f;

  unsigned short* pwave = Pq + w * 2048;

  // ---- preload first tile into buffer 0 ----
  {
    const char* kt = ktile + (size_t)kb0 * (TILE_USH * 2);
    const char* vt = vtile + (size_t)kb0 * (TILE_USH * 2);
    #pragma unroll
    for (int i = 0; i < 4; ++i) {
      const int off = stagebase + i * 1024;
      gl_lds16(kt + off + L * 16, (char*)Khi[0] + off, L);
      gl_lds16(vt + off + L * 16, (char*)Vt[0] + off, L);
    }
  }

  for (int kb = kb0; kb < kbN; ++kb) {
    const int cur = (kb - kb0) & 1;
    __syncthreads();   // drains in-flight loads (issued a full compute phase ago)

    // ---- issue async loads for NEXT tile into the other buffer ----
    if (kb + 1 < kbN) {
      const char* kt = ktile + (size_t)(kb + 1) * (TILE_USH * 2);
      const char* vt = vtile + (size_t)(kb + 1) * (TILE_USH * 2);
      #pragma unroll
      for (int i = 0; i < 4; ++i) {
        const int off = stagebase + i * 1024;
        gl_lds16(kt + off + L * 16, (char*)Khi[cur ^ 1] + off, L);
        gl_lds16(vt + off + L * 16, (char*)Vt[cur ^ 1] + off, L);
      }
    }

    const unsigned short* Kc = Khi[cur];
    const unsigned short* Vc = Vt[cur];

    const float4* mb4 = (const float4*)(mb2g + b * Sn + kb * BK);
    float4 mbv[2][4];
    #pragma unroll
    for (int kg = 0; kg < 2; ++kg)
      #pragma unroll
      for (int ro = 0; ro < 4; ++ro) mbv[kg][ro] = mb4[kg * 8 + ro * 2 + h];

    // ---- S^T = K * Q^T : 2 key-groups x 8 ksteps, hi+lo ----
    floatx16 a32[2];
    #pragma unroll
    for (int kg = 0; kg < 2; ++kg)
      #pragma unroll
      for (int r = 0; r < 16; ++r) a32[kg][r] = 0.0f;
    #pragma unroll
    for (int kstep = 0; kstep < 8; ++kstep) {
      const int ko = ((kstep * 2 + h) ^ sw) * 8;
      #pragma unroll
      for (int kg = 0; kg < 2; ++kg) {
        short8 kf = *(const short8*)&Kc[(kg * 32 + q) * 128 + ko];
        a32[kg] = __builtin_amdgcn_mfma_f32_32x32x16_bf16(kf, qh[kstep], a32[kg], 0, 0, 0);
        a32[kg] = __builtin_amdgcn_mfma_f32_32x32x16_bf16(kf, ql[kstep], a32[kg], 0, 0, 0);
      }
    }

    // ---- online softmax: scale+bias, in-lane reduce, one xor-32 shuffle ----
    #pragma unroll
    for (int kg = 0; kg < 2; ++kg)
      #pragma unroll
      for (int ro = 0; ro < 4; ++ro) {
        float4 f = mbv[kg][ro];
        a32[kg][4 * ro + 0] = fmaf(a32[kg][4 * ro + 0], SC2, f.x);
        a32[kg][4 * ro + 1] = fmaf(a32[kg][4 * ro + 1], SC2, f.y);
        a32[kg][4 * ro + 2] = fmaf(a32[kg][4 * ro + 2], SC2, f.z);
        a32[kg][4 * ro + 3] = fmaf(a32[kg][4 * ro + 3], SC2, f.w);
      }
    float mx = -INFINITY;
    #pragma unroll
    for (int kg = 0; kg < 2; ++kg)
      #pragma unroll
      for (int r = 0; r < 16; ++r) mx = fmaxf(mx, a32[kg][r]);
    mx = fmaxf(mx, __shfl_xor(mx, 32));
    const float mnew = fmaxf(m_i, mx);
    const float alpha = EXP2(m_i - mnew);
    float rs = 0.0f;
    #pragma unroll
    for (int kg = 0; kg < 2; ++kg)
      #pragma unroll
      for (int r = 0; r < 16; ++r) {
        float e = EXP2(a32[kg][r] - mnew);
        a32[kg][r] = e;
        rs += e;
      }
    rs += __shfl_xor(rs, 32);
    l_i = l_i * alpha + rs;
    m_i = mnew;

    // ---- P store: per-wave private [q][key swizzled], packed converts ----
    #pragma unroll
    for (int kg = 0; kg < 2; ++kg)
      #pragma unroll
      for (int ro = 0; ro < 4; ++ro) {
        uint2 u;
        u.x = pack2bf(a32[kg][4 * ro + 0], a32[kg][4 * ro + 1]);
        u.y = pack2bf(a32[kg][4 * ro + 2], a32[kg][4 * ro + 3]);
        const int oct = kg * 4 + ro;
        *(uint2*)&pwave[q * 64 + ((oct ^ sw) * 8) + h * 4] = u;
      }

    if (!__all(alpha == 1.0f)) {
      #pragma unroll
      for (int dg = 0; dg < 4; ++dg)
        #pragma unroll
        for (int r = 0; r < 16; ++r) O32[dg][r] *= alpha;
    }

    // ---- O^T += V^T * P^T : 4 ksteps x 4 d-groups ----
    #pragma unroll
    for (int k2 = 0; k2 < 4; ++k2) {
      const int ko = ((k2 * 2 + h) ^ sw) * 8;
      short8 pf = *(const short8*)&pwave[q * 64 + ko];
      #pragma unroll
      for (int dg = 0; dg < 4; ++dg) {
        short8 vf = *(const short8*)&Vc[(dg * 32 + q) * 64 + ko];
        O32[dg] = __builtin_amdgcn_mfma_f32_32x32x16_bf16(vf, pf, O32[dg], 0, 0, 0);
      }
    }
  }

  // ---- epilogue ----
  const int row = b * Sn + q0 + w * 32 + q;
  if constexpr (DIRECT) {
    const float inv = 1.0f / l_i;
    float* orow = outg + (size_t)row * Dn;
    #pragma unroll
    for (int dg = 0; dg < 4; ++dg)
      #pragma unroll
      for (int ro = 0; ro < 4; ++ro) {
        float4 f = make_float4(O32[dg][4 * ro] * inv,     O32[dg][4 * ro + 1] * inv,
                               O32[dg][4 * ro + 2] * inv, O32[dg][4 * ro + 3] * inv);
        *(float4*)&orow[dg * 32 + 8 * ro + 4 * h] = f;
      }
  } else {
    // write fp16 partials + (m,l)
    __half* orow = Op + ((size_t)s * ROWS + row) * Dn;
    #pragma unroll
    for (int dg = 0; dg < 4; ++dg)
      #pragma unroll
      for (int ro = 0; ro < 4; ++ro) {
        union { __half2 h2[2]; uint2 u; } pk;
        pk.h2[0] = __floats2half2_rn(O32[dg][4 * ro],     O32[dg][4 * ro + 1]);
        pk.h2[1] = __floats2half2_rn(O32[dg][4 * ro + 2], O32[dg][4 * ro + 3]);
        *(uint2*)&orow[dg * 32 + 8 * ro + 4 * h] = pk.u;
      }
    if (h == 0) {
      Mp[s * ROWS + row] = m_i;
      Lp[s * ROWS + row] = l_i;
    }

    // ---- ticket: last split block of this (b,q0) group merges the partials ----
    __threadfence();                              // release partials (device scope)
    if (tid == 0) {
      int old = atomicAdd(&cnt[bid & (NGRP - 1)], 1);
      lastflag = (old == SPLIT - 1) ? 1 : 0;
    }
    __syncthreads();
    if (lastflag) {
      __threadfence();                            // acquire other splits' partials
      float* wrow = (float*)Pq;                   // alias dead P buffer: SPLIT*BQ floats
      const int rowbase0 = b * Sn + q0;
      if (tid < BQ) {
        float ms2[SPLIT];
        float mm = -INFINITY;
        #pragma unroll
        for (int ss = 0; ss < SPLIT; ++ss) {
          ms2[ss] = Mp[ss * ROWS + rowbase0 + tid];
          mm = fmaxf(mm, ms2[ss]);
        }
        float lsum = 0.0f, wv2[SPLIT];
        #pragma unroll
        for (int ss = 0; ss < SPLIT; ++ss) {
          wv2[ss] = EXP2(ms2[ss] - mm);
          lsum = fmaf(Lp[ss * ROWS + rowbase0 + tid], wv2[ss], lsum);
        }
        const float inv = 1.0f / lsum;
        #pragma unroll
        for (int ss = 0; ss < SPLIT; ++ss) wrow[ss * BQ + tid] = wv2[ss] * inv;
      }
      __syncthreads();
      float4* out4 = (float4*)outg;
      const uint2* Op2 = (const uint2*)Op;
      for (int i = tid; i < BQ * (Dn / 4); i += 256) {
        const int rl = i >> 5, c4 = i & 31;
        float4 acc2 = make_float4(0.f, 0.f, 0.f, 0.f);
        #pragma unroll
        for (int ss = 0; ss < SPLIT; ++ss) {
          const float wgt = wrow[ss * BQ + rl];
          union { uint2 u; __half2 h2[2]; } pk;
          pk.u = Op2[((size_t)ss * ROWS + rowbase0 + rl) * 32 + c4];
          float2 f0 = __half22float2(pk.h2[0]);
          float2 f1 = __half22float2(pk.h2[1]);
          acc2.x = fmaf(f0.x, wgt, acc2.x);
          acc2.y = fmaf(f0.y, wgt, acc2.y);
          acc2.z = fmaf(f1.x, wgt, acc2.z);
          acc2.w = fmaf(f1.y, wgt, acc2.w);
        }
        out4[(size_t)(rowbase0 + rl) * 32 + c4] = acc2;
      }
    }
  }
}

extern "C" void kernel_launch(void* const* d_in, const int* in_sizes, int n_in,
                              void* d_out, int out_size, void* d_ws, size_t ws_size,
                              hipStream_t stream) {
  const float* q = (const float*)d_in[0];
  const float* k = (const float*)d_in[1];
  const float* v = (const float*)d_in[2];
  const unsigned char* m = (const unsigned char*)d_in[3];
  float* out = (float*)d_out;
  (void)in_sizes; (void)n_in; (void)out_size;

  constexpr size_t OPB = (size_t)NSPLIT * ROWS * Dn * sizeof(__half); // 16.8 MB
  constexpr size_t MLB = (size_t)NSPLIT * ROWS * sizeof(float);       // 256 KB
  constexpr size_t KPB = (size_t)Bn * NKB * TILE_USH * 2;             // 4 MB
  constexpr size_t MBB = (size_t)ROWS * sizeof(float);                // 64 KB
  constexpr size_t CNT = (size_t)NGRP * sizeof(int);                  // 512 B

  char* ws = (char*)d_ws;
  if (ws_size >= OPB + 2 * MLB + 2 * KPB + MBB + CNT) {
    __half* Op = (__half*)ws;
    float* Mp = (float*)(ws + OPB);
    float* Lp = (float*)(ws + OPB + MLB);
    unsigned short* Kp = (unsigned short*)(ws + OPB + 2 * MLB);
    unsigned short* Vp = (unsigned short*)(ws + OPB + 2 * MLB + KPB);
    float* mb2 = (float*)(ws + OPB + 2 * MLB + 2 * KPB);
    int* cnt = (int*)(ws + OPB + 2 * MLB + 2 * KPB + MBB);
    prep<<<dim3(Bn * NKB * 4), dim3(256), 0, stream>>>(k, v, m, Kp, Vp, mb2, cnt);
    attn_fwd<NSPLIT, false><<<dim3(Bn * QTILES * NSPLIT), dim3(256), 0, stream>>>(
        q, Kp, Vp, mb2, out, Op, Mp, Lp, cnt);
  } else if (ws_size >= 2 * KPB + MBB + CNT) {
    unsigned short* Kp = (unsigned short*)ws;
    unsigned short* Vp = (unsigned short*)(ws + KPB);
    float* mb2 = (float*)(ws + 2 * KPB);
    int* cnt = (int*)(ws + 2 * KPB + MBB);
    prep<<<dim3(Bn * NKB * 4), dim3(256), 0, stream>>>(k, v, m, Kp, Vp, mb2, cnt);
    attn_fwd<1, true><<<dim3(Bn * QTILES), dim3(256), 0, stream>>>(
        q, Kp, Vp, mb2, out, nullptr, nullptr, nullptr, cnt);
  }
}

// Round 10
// 198.683 us; speedup vs baseline: 1.0435x; 1.0435x over previous
//
#include <hip/hip_runtime.h>
#include <hip/hip_fp16.h>
#include <math.h>

typedef __attribute__((ext_vector_type(8))) short short8;
typedef __attribute__((ext_vector_type(16))) float floatx16;
typedef __attribute__((ext_vector_type(2))) __bf16 bf16x2;

namespace {
constexpr int Bn = 8;
constexpr int Sn = 2048;
constexpr int Dn = 128;
constexpr int BQ = 128;                // queries per block (4 waves x 32)
constexpr int BK = 64;                 // keys per tile
constexpr int QTILES = Sn / BQ;        // 16
constexpr int NKB = Sn / BK;           // 32
constexpr int ROWS = Bn * Sn;          // 16384
constexpr int NSPLIT = 4;              // grid 512 blocks(256thr) = 2 blocks/CU
constexpr int NGRP = Bn * QTILES;      // 128 (b,q0) groups
constexpr float SC2 = 0.12753102063642597f;  // (1/sqrt(128)) * log2(e)
constexpr int TILE_USH = BK * Dn;      // 8192 ushorts = 16 KB tile
}

#if __has_builtin(__builtin_amdgcn_exp2f)
#define EXP2(x) __builtin_amdgcn_exp2f(x)
#else
#define EXP2(x) exp2f(x)
#endif

__device__ __forceinline__ unsigned short f2bf(float x) {
  union { float f; unsigned u; } a; a.f = x;
  unsigned r = a.u + 0x7fffu + ((a.u >> 16) & 1u);   // RNE
  return (unsigned short)(r >> 16);
}

// HW packed convert: 2 floats -> bf16x2 (v_cvt_pk_bf16_f32)
__device__ __forceinline__ unsigned pack2bf(float x, float y) {
  union { bf16x2 b; unsigned u; } c;
  c.b[0] = (__bf16)x; c.b[1] = (__bf16)y;
  return c.u;
}

__device__ __forceinline__ void gl_lds16(const void* g, void* l, int lane) {
#if __has_builtin(__builtin_amdgcn_global_load_lds)
  (void)lane;
  __builtin_amdgcn_global_load_lds((const __attribute__((address_space(1))) unsigned int*)g,
                                   (__attribute__((address_space(3))) unsigned int*)l, 16, 0, 0);
#else
  *(float4*)((char*)l + lane * 16) = *(const float4*)g;
#endif
}

// ---------------- pre-pass (1024 blocks x 256 thr, 16 keys each):
// K -> bf16 swizzled tiles [key][oct(d>>3)^(key&7)], V -> bf16 transposed tiles
// [d][oct(key>>3)^(d&7)], mask -> bias floats, zero split-K ticket counters.
__global__ __launch_bounds__(256)
void prep(const float* __restrict__ kg, const float* __restrict__ vg,
          const unsigned char* __restrict__ mraw,
          unsigned short* __restrict__ Kpg, unsigned short* __restrict__ Vpg,
          float* __restrict__ mb2g, int* __restrict__ cnt) {
  __shared__ __align__(16) float Vf[16 * 136];
  const int p = blockIdx.x;
  const int b = p >> 7, q = p & 127;
  const int kb = q >> 2, k16 = q & 3;
  const int t = threadIdx.x;

  if (p == 0 && t < NGRP) cnt[t] = 0;   // stream-ordered before attn_fwd

  unsigned wv = ((const unsigned int*)mraw)[t];
  int any1  = __syncthreads_or((wv & 0x0000ff00u) ? 1 : 0);
  int any23 = __syncthreads_or((wv & 0xffff0000u) ? 1 : 0);
  const int mlayout = any1 ? 1 : (any23 ? 2 : 0);
  if (p < 64) {
    int idx = p * 256 + t;
    bool ms;
    if (mlayout == 1)      ms = mraw[idx] != 0;
    else if (mlayout == 2) ms = ((const float*)mraw)[idx] != 0.0f;
    else                   ms = ((const int*)mraw)[idx] != 0;
    mb2g[idx] = ms ? -1e30f : 0.0f;
  }

  const int j  = t >> 4;
  const int o8 = t & 15;
  const size_t base = ((size_t)(b * Sn + kb * 64 + k16 * 16 + j)) * 32 + o8 * 2;
  const float4* k4 = (const float4*)kg;
  const float4* v4 = (const float4*)vg;

  {
    float4 a = k4[base], bq = k4[base + 1];
    union { unsigned u[4]; short8 s8; } pk;
    pk.u[0] = pack2bf(a.x, a.y);   pk.u[1] = pack2bf(a.z, a.w);
    pk.u[2] = pack2bf(bq.x, bq.y); pk.u[3] = pack2bf(bq.z, bq.w);
    const int jl = k16 * 16 + j;
    *(short8*)(Kpg + (size_t)(b * NKB + kb) * TILE_USH + jl * 128 + ((o8 ^ (jl & 7)) * 8)) = pk.s8;
  }
  {
    float4 a = v4[base], bq = v4[base + 1];
    *(float4*)&Vf[j * 136 + o8 * 8]     = a;
    *(float4*)&Vf[j * 136 + o8 * 8 + 4] = bq;
  }
  __syncthreads();
  {
    const int d = t >> 1, h = t & 1;
    union { unsigned u[4]; short8 s8; } pv;
    #pragma unroll
    for (int i = 0; i < 4; ++i)
      pv.u[i] = pack2bf(Vf[(h * 8 + 2 * i) * 136 + d], Vf[(h * 8 + 2 * i + 1) * 136 + d]);
    const int og = k16 * 2 + h;
    *(short8*)(Vpg + (size_t)(b * NKB + kb) * TILE_USH + d * 64 + ((og ^ (d & 7)) * 8)) = pv.s8;
  }
}

// ---------------- main flash kernel, mfma_f32_32x32x16_bf16, double-buffered K-loop,
// fused split-K combine. LDS EXACTLY 81920 B = 160KiB/2 -> 2 blocks/CU.
// (R9 lesson: one extra __shared__ int pushed LDS to 82432 -> 1 block/CU -> 2x slower.)
template<int SPLIT, bool DIRECT>
__global__ __launch_bounds__(256, 2)
void attn_fwd(const float* __restrict__ qg,
              const unsigned short* __restrict__ Kpg,
              const unsigned short* __restrict__ Vpg,
              const float* __restrict__ mb2g,
              float* __restrict__ outg, __half* __restrict__ Op,
              float* __restrict__ Mp, float* __restrict__ Lp,
              int* __restrict__ cnt) {
  __shared__ __align__(16) unsigned short Khi[2][TILE_USH];  // 32768 B
  __shared__ __align__(16) unsigned short Vt[2][TILE_USH];   // 32768 B
  __shared__ __align__(16) unsigned short Pq[4 * 2048];      // 16384 B
  // lastflag aliased into Pq (dead by epilogue): word 4000 (wrow uses words 0..511)
  int* lastflag = (int*)Pq + 4000;

  const int tid = threadIdx.x;
  const int bid = blockIdx.x;
  const int b   = bid & 7;                       // batch -> XCD swizzle
  const int q0  = ((bid >> 3) & (QTILES - 1)) * BQ;
  const int s   = bid >> 7;                      // split index (0 when SPLIT==1)
  const int kb0 = s * (NKB / SPLIT);
  const int kbN = kb0 + NKB / SPLIT;
  const int w   = tid >> 6;                      // wave 0..3
  const int L   = tid & 63;
  const int q   = L & 31;                        // query within wave
  const int h   = L >> 5;                        // k-half selector
  const int sw  = q & 7;                         // octet XOR swizzle key

  const char* ktile = (const char*)(Kpg + (size_t)b * NKB * TILE_USH);
  const char* vtile = (const char*)(Vpg + (size_t)b * NKB * TILE_USH);
  const int stagebase = w * 4096;                // wave's quarter of a 16 KB tile

  // Q B-fragments: lane holds Q[row q][d = kstep*16 + h*8 + j], hi/lo split
  short8 qh[8], ql[8];
  {
    const float* qrow = qg + (size_t)(b * Sn + q0 + w * 32 + q) * Dn;
    #pragma unroll
    for (int kstep = 0; kstep < 8; ++kstep) {
      float4 f0 = *(const float4*)(qrow + kstep * 16 + h * 8);
      float4 f1 = *(const float4*)(qrow + kstep * 16 + h * 8 + 4);
      float xs[8] = {f0.x, f0.y, f0.z, f0.w, f1.x, f1.y, f1.z, f1.w};
      #pragma unroll
      for (int j = 0; j < 8; ++j) {
        unsigned short hi = f2bf(xs[j]);
        union { unsigned u; float f; } hv; hv.u = ((unsigned)hi) << 16;
        qh[kstep][j] = (short)hi;
        ql[kstep][j] = (short)f2bf(xs[j] - hv.f);
      }
    }
  }

  float m_i = -INFINITY, l_i = 0.0f;
  floatx16 O32[4];
  #pragma unroll
  for (int dg = 0; dg < 4; ++dg)
    #pragma unroll
    for (int r = 0; r < 16; ++r) O32[dg][r] = 0.0f;

  unsigned short* pwave = Pq + w * 2048;

  // ---- preload first tile into buffer 0 ----
  {
    const char* kt = ktile + (size_t)kb0 * (TILE_USH * 2);
    const char* vt = vtile + (size_t)kb0 * (TILE_USH * 2);
    #pragma unroll
    for (int i = 0; i < 4; ++i) {
      const int off = stagebase + i * 1024;
      gl_lds16(kt + off + L * 16, (char*)Khi[0] + off, L);
      gl_lds16(vt + off + L * 16, (char*)Vt[0] + off, L);
    }
  }

  for (int kb = kb0; kb < kbN; ++kb) {
    const int cur = (kb - kb0) & 1;
    __syncthreads();   // drains in-flight loads (issued a full compute phase ago)

    // ---- issue async loads for NEXT tile into the other buffer ----
    if (kb + 1 < kbN) {
      const char* kt = ktile + (size_t)(kb + 1) * (TILE_USH * 2);
      const char* vt = vtile + (size_t)(kb + 1) * (TILE_USH * 2);
      #pragma unroll
      for (int i = 0; i < 4; ++i) {
        const int off = stagebase + i * 1024;
        gl_lds16(kt + off + L * 16, (char*)Khi[cur ^ 1] + off, L);
        gl_lds16(vt + off + L * 16, (char*)Vt[cur ^ 1] + off, L);
      }
    }

    const unsigned short* Kc = Khi[cur];
    const unsigned short* Vc = Vt[cur];

    const float4* mb4 = (const float4*)(mb2g + b * Sn + kb * BK);
    float4 mbv[2][4];
    #pragma unroll
    for (int kg = 0; kg < 2; ++kg)
      #pragma unroll
      for (int ro = 0; ro < 4; ++ro) mbv[kg][ro] = mb4[kg * 8 + ro * 2 + h];

    // ---- S^T = K * Q^T : 2 key-groups x 8 ksteps, hi+lo ----
    floatx16 a32[2];
    #pragma unroll
    for (int kg = 0; kg < 2; ++kg)
      #pragma unroll
      for (int r = 0; r < 16; ++r) a32[kg][r] = 0.0f;
    #pragma unroll
    for (int kstep = 0; kstep < 8; ++kstep) {
      const int ko = ((kstep * 2 + h) ^ sw) * 8;
      #pragma unroll
      for (int kg = 0; kg < 2; ++kg) {
        short8 kf = *(const short8*)&Kc[(kg * 32 + q) * 128 + ko];
        a32[kg] = __builtin_amdgcn_mfma_f32_32x32x16_bf16(kf, qh[kstep], a32[kg], 0, 0, 0);
        a32[kg] = __builtin_amdgcn_mfma_f32_32x32x16_bf16(kf, ql[kstep], a32[kg], 0, 0, 0);
      }
    }

    // ---- online softmax: scale+bias, in-lane reduce, one xor-32 shuffle ----
    #pragma unroll
    for (int kg = 0; kg < 2; ++kg)
      #pragma unroll
      for (int ro = 0; ro < 4; ++ro) {
        float4 f = mbv[kg][ro];
        a32[kg][4 * ro + 0] = fmaf(a32[kg][4 * ro + 0], SC2, f.x);
        a32[kg][4 * ro + 1] = fmaf(a32[kg][4 * ro + 1], SC2, f.y);
        a32[kg][4 * ro + 2] = fmaf(a32[kg][4 * ro + 2], SC2, f.z);
        a32[kg][4 * ro + 3] = fmaf(a32[kg][4 * ro + 3], SC2, f.w);
      }
    float mx = -INFINITY;
    #pragma unroll
    for (int kg = 0; kg < 2; ++kg)
      #pragma unroll
      for (int r = 0; r < 16; ++r) mx = fmaxf(mx, a32[kg][r]);
    mx = fmaxf(mx, __shfl_xor(mx, 32));
    const float mnew = fmaxf(m_i, mx);
    const float alpha = EXP2(m_i - mnew);
    float rs = 0.0f;
    #pragma unroll
    for (int kg = 0; kg < 2; ++kg)
      #pragma unroll
      for (int r = 0; r < 16; ++r) {
        float e = EXP2(a32[kg][r] - mnew);
        a32[kg][r] = e;
        rs += e;
      }
    rs += __shfl_xor(rs, 32);
    l_i = l_i * alpha + rs;
    m_i = mnew;

    // ---- P store: per-wave private [q][key swizzled], packed converts ----
    #pragma unroll
    for (int kg = 0; kg < 2; ++kg)
      #pragma unroll
      for (int ro = 0; ro < 4; ++ro) {
        uint2 u;
        u.x = pack2bf(a32[kg][4 * ro + 0], a32[kg][4 * ro + 1]);
        u.y = pack2bf(a32[kg][4 * ro + 2], a32[kg][4 * ro + 3]);
        const int oct = kg * 4 + ro;
        *(uint2*)&pwave[q * 64 + ((oct ^ sw) * 8) + h * 4] = u;
      }

    if (!__all(alpha == 1.0f)) {
      #pragma unroll
      for (int dg = 0; dg < 4; ++dg)
        #pragma unroll
        for (int r = 0; r < 16; ++r) O32[dg][r] *= alpha;
    }

    // ---- O^T += V^T * P^T : 4 ksteps x 4 d-groups ----
    #pragma unroll
    for (int k2 = 0; k2 < 4; ++k2) {
      const int ko = ((k2 * 2 + h) ^ sw) * 8;
      short8 pf = *(const short8*)&pwave[q * 64 + ko];
      #pragma unroll
      for (int dg = 0; dg < 4; ++dg) {
        short8 vf = *(const short8*)&Vc[(dg * 32 + q) * 64 + ko];
        O32[dg] = __builtin_amdgcn_mfma_f32_32x32x16_bf16(vf, pf, O32[dg], 0, 0, 0);
      }
    }
  }

  // ---- epilogue ----
  const int row = b * Sn + q0 + w * 32 + q;
  if constexpr (DIRECT) {
    const float inv = 1.0f / l_i;
    float* orow = outg + (size_t)row * Dn;
    #pragma unroll
    for (int dg = 0; dg < 4; ++dg)
      #pragma unroll
      for (int ro = 0; ro < 4; ++ro) {
        float4 f = make_float4(O32[dg][4 * ro] * inv,     O32[dg][4 * ro + 1] * inv,
                               O32[dg][4 * ro + 2] * inv, O32[dg][4 * ro + 3] * inv);
        *(float4*)&orow[dg * 32 + 8 * ro + 4 * h] = f;
      }
  } else {
    // write fp16 partials + (m,l)
    __half* orow = Op + ((size_t)s * ROWS + row) * Dn;
    #pragma unroll
    for (int dg = 0; dg < 4; ++dg)
      #pragma unroll
      for (int ro = 0; ro < 4; ++ro) {
        union { __half2 h2[2]; uint2 u; } pk;
        pk.h2[0] = __floats2half2_rn(O32[dg][4 * ro],     O32[dg][4 * ro + 1]);
        pk.h2[1] = __floats2half2_rn(O32[dg][4 * ro + 2], O32[dg][4 * ro + 3]);
        *(uint2*)&orow[dg * 32 + 8 * ro + 4 * h] = pk.u;
      }
    if (h == 0) {
      Mp[s * ROWS + row] = m_i;
      Lp[s * ROWS + row] = l_i;
    }

    // ---- ticket: last split block of this (b,q0) group merges the partials ----
    __threadfence();                              // release partials (device scope)
    if (tid == 0) {
      int old = atomicAdd(&cnt[bid & (NGRP - 1)], 1);
      *lastflag = (old == SPLIT - 1) ? 1 : 0;
    }
    __syncthreads();
    if (*lastflag) {
      __threadfence();                            // acquire other splits' partials
      float* wrow = (float*)Pq;                   // words 0..511 (lastflag at 4000)
      const int rowbase0 = b * Sn + q0;
      if (tid < BQ) {
        float ms2[SPLIT];
        float mm = -INFINITY;
        #pragma unroll
        for (int ss = 0; ss < SPLIT; ++ss) {
          ms2[ss] = Mp[ss * ROWS + rowbase0 + tid];
          mm = fmaxf(mm, ms2[ss]);
        }
        float lsum = 0.0f, wv2[SPLIT];
        #pragma unroll
        for (int ss = 0; ss < SPLIT; ++ss) {
          wv2[ss] = EXP2(ms2[ss] - mm);
          lsum = fmaf(Lp[ss * ROWS + rowbase0 + tid], wv2[ss], lsum);
        }
        const float inv = 1.0f / lsum;
        #pragma unroll
        for (int ss = 0; ss < SPLIT; ++ss) wrow[ss * BQ + tid] = wv2[ss] * inv;
      }
      __syncthreads();
      float4* out4 = (float4*)outg;
      const uint2* Op2 = (const uint2*)Op;
      for (int i = tid; i < BQ * (Dn / 4); i += 256) {
        const int rl = i >> 5, c4 = i & 31;
        float4 acc2 = make_float4(0.f, 0.f, 0.f, 0.f);
        #pragma unroll
        for (int ss = 0; ss < SPLIT; ++ss) {
          const float wgt = wrow[ss * BQ + rl];
          union { uint2 u; __half2 h2[2]; } pk;
          pk.u = Op2[((size_t)ss * ROWS + rowbase0 + rl) * 32 + c4];
          float2 f0 = __half22float2(pk.h2[0]);
          float2 f1 = __half22float2(pk.h2[1]);
          acc2.x = fmaf(f0.x, wgt, acc2.x);
          acc2.y = fmaf(f0.y, wgt, acc2.y);
          acc2.z = fmaf(f1.x, wgt, acc2.z);
          acc2.w = fmaf(f1.y, wgt, acc2.w);
        }
        out4[(size_t)(rowbase0 + rl) * 32 + c4] = acc2;
      }
    }
  }
}

extern "C" void kernel_launch(void* const* d_in, const int* in_sizes, int n_in,
                              void* d_out, int out_size, void* d_ws, size_t ws_size,
                              hipStream_t stream) {
  const float* q = (const float*)d_in[0];
  const float* k = (const float*)d_in[1];
  const float* v = (const float*)d_in[2];
  const unsigned char* m = (const unsigned char*)d_in[3];
  float* out = (float*)d_out;
  (void)in_sizes; (void)n_in; (void)out_size;

  constexpr size_t OPB = (size_t)NSPLIT * ROWS * Dn * sizeof(__half); // 16.8 MB
  constexpr size_t MLB = (size_t)NSPLIT * ROWS * sizeof(float);       // 256 KB
  constexpr size_t KPB = (size_t)Bn * NKB * TILE_USH * 2;             // 4 MB
  constexpr size_t MBB = (size_t)ROWS * sizeof(float);                // 64 KB
  constexpr size_t CNT = (size_t)NGRP * sizeof(int);                  // 512 B

  char* ws = (char*)d_ws;
  if (ws_size >= OPB + 2 * MLB + 2 * KPB + MBB + CNT) {
    __half* Op = (__half*)ws;
    float* Mp = (float*)(ws + OPB);
    float* Lp = (float*)(ws + OPB + MLB);
    unsigned short* Kp = (unsigned short*)(ws + OPB + 2 * MLB);
    unsigned short* Vp = (unsigned short*)(ws + OPB + 2 * MLB + KPB);
    float* mb2 = (float*)(ws + OPB + 2 * MLB + 2 * KPB);
    int* cnt = (int*)(ws + OPB + 2 * MLB + 2 * KPB + MBB);
    prep<<<dim3(Bn * NKB * 4), dim3(256), 0, stream>>>(k, v, m, Kp, Vp, mb2, cnt);
    attn_fwd<NSPLIT, false><<<dim3(Bn * QTILES * NSPLIT), dim3(256), 0, stream>>>(
        q, Kp, Vp, mb2, out, Op, Mp, Lp, cnt);
  } else if (ws_size >= 2 * KPB + MBB + CNT) {
    unsigned short* Kp = (unsigned short*)ws;
    unsigned short* Vp = (unsigned short*)(ws + KPB);
    float* mb2 = (float*)(ws + 2 * KPB);
    int* cnt = (int*)(ws + 2 * KPB + MBB);
    prep<<<dim3(Bn * NKB * 4), dim3(256), 0, stream>>>(k, v, m, Kp, Vp, mb2, cnt);
    attn_fwd<1, true><<<dim3(Bn * QTILES), dim3(256), 0, stream>>>(
        q, Kp, Vp, mb2, out, nullptr, nullptr, nullptr, cnt);
  }
}

// Round 11
// 114.450 us; speedup vs baseline: 1.8115x; 1.7360x over previous
//
#include <hip/hip_runtime.h>
#include <hip/hip_fp16.h>
#include <math.h>

typedef __attribute__((ext_vector_type(8))) short short8;
typedef __attribute__((ext_vector_type(16))) float floatx16;
typedef __attribute__((ext_vector_type(2))) __bf16 bf16x2;

namespace {
constexpr int Bn = 8;
constexpr int Sn = 2048;
constexpr int Dn = 128;
constexpr int BQ = 128;                // queries per block (4 waves x 32)
constexpr int BK = 64;                 // keys per tile
constexpr int QTILES = Sn / BQ;        // 16
constexpr int NKB = Sn / BK;           // 32
constexpr int ROWS = Bn * Sn;          // 16384
constexpr int NSPLIT = 4;              // grid 512 blocks(256thr) = 2 blocks/CU
constexpr float SC2 = 0.12753102063642597f;  // (1/sqrt(128)) * log2(e)
constexpr int TILE_USH = BK * Dn;      // 8192 ushorts = 16 KB tile
}

#if __has_builtin(__builtin_amdgcn_exp2f)
#define EXP2(x) __builtin_amdgcn_exp2f(x)
#else
#define EXP2(x) exp2f(x)
#endif

__device__ __forceinline__ unsigned short f2bf(float x) {
  union { float f; unsigned u; } a; a.f = x;
  unsigned r = a.u + 0x7fffu + ((a.u >> 16) & 1u);   // RNE
  return (unsigned short)(r >> 16);
}

// HW packed convert: 2 floats -> bf16x2 (v_cvt_pk_bf16_f32)
__device__ __forceinline__ unsigned pack2bf(float x, float y) {
  union { bf16x2 b; unsigned u; } c;
  c.b[0] = (__bf16)x; c.b[1] = (__bf16)y;
  return c.u;
}

__device__ __forceinline__ void gl_lds16(const void* g, void* l, int lane) {
#if __has_builtin(__builtin_amdgcn_global_load_lds)
  (void)lane;
  __builtin_amdgcn_global_load_lds((const __attribute__((address_space(1))) unsigned int*)g,
                                   (__attribute__((address_space(3))) unsigned int*)l, 16, 0, 0);
#else
  *(float4*)((char*)l + lane * 16) = *(const float4*)g;
#endif
}

// ---------------- pre-pass (1024 blocks x 256 thr, 16 keys each):
// K -> bf16 swizzled tiles [key][oct(d>>3)^(key&7)], V -> bf16 transposed tiles
// [d][oct(key>>3)^(d&7)], mask -> bias floats. Unchanged (verified since R6).
__global__ __launch_bounds__(256)
void prep(const float* __restrict__ kg, const float* __restrict__ vg,
          const unsigned char* __restrict__ mraw,
          unsigned short* __restrict__ Kpg, unsigned short* __restrict__ Vpg,
          float* __restrict__ mb2g) {
  __shared__ __align__(16) float Vf[16 * 136];
  const int p = blockIdx.x;
  const int b = p >> 7, q = p & 127;
  const int kb = q >> 2, k16 = q & 3;
  const int t = threadIdx.x;

  unsigned wv = ((const unsigned int*)mraw)[t];
  int any1  = __syncthreads_or((wv & 0x0000ff00u) ? 1 : 0);
  int any23 = __syncthreads_or((wv & 0xffff0000u) ? 1 : 0);
  const int mlayout = any1 ? 1 : (any23 ? 2 : 0);
  if (p < 64) {
    int idx = p * 256 + t;
    bool ms;
    if (mlayout == 1)      ms = mraw[idx] != 0;
    else if (mlayout == 2) ms = ((const float*)mraw)[idx] != 0.0f;
    else                   ms = ((const int*)mraw)[idx] != 0;
    mb2g[idx] = ms ? -1e30f : 0.0f;
  }

  const int j  = t >> 4;
  const int o8 = t & 15;
  const size_t base = ((size_t)(b * Sn + kb * 64 + k16 * 16 + j)) * 32 + o8 * 2;
  const float4* k4 = (const float4*)kg;
  const float4* v4 = (const float4*)vg;

  {
    float4 a = k4[base], bq = k4[base + 1];
    union { unsigned u[4]; short8 s8; } pk;
    pk.u[0] = pack2bf(a.x, a.y);   pk.u[1] = pack2bf(a.z, a.w);
    pk.u[2] = pack2bf(bq.x, bq.y); pk.u[3] = pack2bf(bq.z, bq.w);
    const int jl = k16 * 16 + j;
    *(short8*)(Kpg + (size_t)(b * NKB + kb) * TILE_USH + jl * 128 + ((o8 ^ (jl & 7)) * 8)) = pk.s8;
  }
  {
    float4 a = v4[base], bq = v4[base + 1];
    *(float4*)&Vf[j * 136 + o8 * 8]     = a;
    *(float4*)&Vf[j * 136 + o8 * 8 + 4] = bq;
  }
  __syncthreads();
  {
    const int d = t >> 1, h = t & 1;
    union { unsigned u[4]; short8 s8; } pv;
    #pragma unroll
    for (int i = 0; i < 4; ++i)
      pv.u[i] = pack2bf(Vf[(h * 8 + 2 * i) * 136 + d], Vf[(h * 8 + 2 * i + 1) * 136 + d]);
    const int og = k16 * 2 + h;
    *(short8*)(Vpg + (size_t)(b * NKB + kb) * TILE_USH + d * 64 + ((og ^ (d & 7)) * 8)) = pv.s8;
  }
}

// ---------------- main flash kernel, mfma_f32_32x32x16_bf16, double-buffered K-loop.
// R8 structure (best measured). NO fences/atomics (R9/R10 lesson: device-scope
// __threadfence per block costs ~95us in L2 writebacks on gfx950).
// LDS exactly 81920 B = 160KiB/2 -> 2 blocks/CU (R9 lesson: +4B -> 1 block/CU).
template<int SPLIT, bool DIRECT>
__global__ __launch_bounds__(256, 2)
void attn_fwd(const float* __restrict__ qg,
              const unsigned short* __restrict__ Kpg,
              const unsigned short* __restrict__ Vpg,
              const float* __restrict__ mb2g,
              float* __restrict__ outg, __half* __restrict__ Op,
              float* __restrict__ Mp, float* __restrict__ Lp) {
  __shared__ __align__(16) unsigned short Khi[2][TILE_USH];  // 32768 B
  __shared__ __align__(16) unsigned short Vt[2][TILE_USH];   // 32768 B
  __shared__ __align__(16) unsigned short Pq[4 * 2048];      // 16384 B

  const int tid = threadIdx.x;
  const int bid = blockIdx.x;
  const int b   = bid & 7;                       // batch -> XCD swizzle
  const int q0  = ((bid >> 3) & (QTILES - 1)) * BQ;
  const int s   = bid >> 7;                      // split index (0 when SPLIT==1)
  const int kb0 = s * (NKB / SPLIT);
  const int kbN = kb0 + NKB / SPLIT;
  const int w   = tid >> 6;                      // wave 0..3
  const int L   = tid & 63;
  const int q   = L & 31;                        // query within wave
  const int h   = L >> 5;                        // k-half selector
  const int sw  = q & 7;                         // octet XOR swizzle key

  const char* ktile = (const char*)(Kpg + (size_t)b * NKB * TILE_USH);
  const char* vtile = (const char*)(Vpg + (size_t)b * NKB * TILE_USH);
  const int stagebase = w * 4096;                // wave's quarter of a 16 KB tile

  // ---- issue first tile staging FIRST so Q-load latency overlaps it ----
  {
    const char* kt = ktile + (size_t)kb0 * (TILE_USH * 2);
    const char* vt = vtile + (size_t)kb0 * (TILE_USH * 2);
    #pragma unroll
    for (int i = 0; i < 4; ++i) {
      const int off = stagebase + i * 1024;
      gl_lds16(kt + off + L * 16, (char*)Khi[0] + off, L);
      gl_lds16(vt + off + L * 16, (char*)Vt[0] + off, L);
    }
  }

  // Q B-fragments: lane holds Q[row q][d = kstep*16 + h*8 + j], hi/lo split
  short8 qh[8], ql[8];
  {
    const float* qrow = qg + (size_t)(b * Sn + q0 + w * 32 + q) * Dn;
    #pragma unroll
    for (int kstep = 0; kstep < 8; ++kstep) {
      float4 f0 = *(const float4*)(qrow + kstep * 16 + h * 8);
      float4 f1 = *(const float4*)(qrow + kstep * 16 + h * 8 + 4);
      float xs[8] = {f0.x, f0.y, f0.z, f0.w, f1.x, f1.y, f1.z, f1.w};
      #pragma unroll
      for (int j = 0; j < 8; ++j) {
        unsigned short hi = f2bf(xs[j]);
        union { unsigned u; float f; } hv; hv.u = ((unsigned)hi) << 16;
        qh[kstep][j] = (short)hi;
        ql[kstep][j] = (short)f2bf(xs[j] - hv.f);
      }
    }
  }

  float m_i = -INFINITY, l_i = 0.0f;
  floatx16 O32[4];
  #pragma unroll
  for (int dg = 0; dg < 4; ++dg)
    #pragma unroll
    for (int r = 0; r < 16; ++r) O32[dg][r] = 0.0f;

  unsigned short* pwave = Pq + w * 2048;

  for (int kb = kb0; kb < kbN; ++kb) {
    const int cur = (kb - kb0) & 1;
    __syncthreads();   // drains in-flight loads (issued a full compute phase ago)

    // ---- issue async loads for NEXT tile into the other buffer ----
    if (kb + 1 < kbN) {
      const char* kt = ktile + (size_t)(kb + 1) * (TILE_USH * 2);
      const char* vt = vtile + (size_t)(kb + 1) * (TILE_USH * 2);
      #pragma unroll
      for (int i = 0; i < 4; ++i) {
        const int off = stagebase + i * 1024;
        gl_lds16(kt + off + L * 16, (char*)Khi[cur ^ 1] + off, L);
        gl_lds16(vt + off + L * 16, (char*)Vt[cur ^ 1] + off, L);
      }
    }

    const unsigned short* Kc = Khi[cur];
    const unsigned short* Vc = Vt[cur];

    const float4* mb4 = (const float4*)(mb2g + b * Sn + kb * BK);
    float4 mbv[2][4];
    #pragma unroll
    for (int kg = 0; kg < 2; ++kg)
      #pragma unroll
      for (int ro = 0; ro < 4; ++ro) mbv[kg][ro] = mb4[kg * 8 + ro * 2 + h];

    // ---- S^T = K * Q^T : 2 key-groups x 8 ksteps, hi+lo ----
    floatx16 a32[2];
    #pragma unroll
    for (int kg = 0; kg < 2; ++kg)
      #pragma unroll
      for (int r = 0; r < 16; ++r) a32[kg][r] = 0.0f;
    #pragma unroll
    for (int kstep = 0; kstep < 8; ++kstep) {
      const int ko = ((kstep * 2 + h) ^ sw) * 8;
      #pragma unroll
      for (int kg = 0; kg < 2; ++kg) {
        short8 kf = *(const short8*)&Kc[(kg * 32 + q) * 128 + ko];
        a32[kg] = __builtin_amdgcn_mfma_f32_32x32x16_bf16(kf, qh[kstep], a32[kg], 0, 0, 0);
        a32[kg] = __builtin_amdgcn_mfma_f32_32x32x16_bf16(kf, ql[kstep], a32[kg], 0, 0, 0);
      }
    }

    // ---- online softmax: scale+bias, in-lane reduce, one xor-32 shuffle ----
    #pragma unroll
    for (int kg = 0; kg < 2; ++kg)
      #pragma unroll
      for (int ro = 0; ro < 4; ++ro) {
        float4 f = mbv[kg][ro];
        a32[kg][4 * ro + 0] = fmaf(a32[kg][4 * ro + 0], SC2, f.x);
        a32[kg][4 * ro + 1] = fmaf(a32[kg][4 * ro + 1], SC2, f.y);
        a32[kg][4 * ro + 2] = fmaf(a32[kg][4 * ro + 2], SC2, f.z);
        a32[kg][4 * ro + 3] = fmaf(a32[kg][4 * ro + 3], SC2, f.w);
      }
    float mx = -INFINITY;
    #pragma unroll
    for (int kg = 0; kg < 2; ++kg)
      #pragma unroll
      for (int r = 0; r < 16; ++r) mx = fmaxf(mx, a32[kg][r]);
    mx = fmaxf(mx, __shfl_xor(mx, 32));
    const float mnew = fmaxf(m_i, mx);
    const float alpha = EXP2(m_i - mnew);
    float rs = 0.0f;
    #pragma unroll
    for (int kg = 0; kg < 2; ++kg)
      #pragma unroll
      for (int r = 0; r < 16; ++r) {
        float e = EXP2(a32[kg][r] - mnew);
        a32[kg][r] = e;
        rs += e;
      }
    rs += __shfl_xor(rs, 32);
    l_i = l_i * alpha + rs;
    m_i = mnew;

    // ---- P store: per-wave private [q][key swizzled], packed converts ----
    #pragma unroll
    for (int kg = 0; kg < 2; ++kg)
      #pragma unroll
      for (int ro = 0; ro < 4; ++ro) {
        uint2 u;
        u.x = pack2bf(a32[kg][4 * ro + 0], a32[kg][4 * ro + 1]);
        u.y = pack2bf(a32[kg][4 * ro + 2], a32[kg][4 * ro + 3]);
        const int oct = kg * 4 + ro;
        *(uint2*)&pwave[q * 64 + ((oct ^ sw) * 8) + h * 4] = u;
      }

    if (!__all(alpha == 1.0f)) {
      #pragma unroll
      for (int dg = 0; dg < 4; ++dg)
        #pragma unroll
        for (int r = 0; r < 16; ++r) O32[dg][r] *= alpha;
    }

    // ---- O^T += V^T * P^T : 4 ksteps x 4 d-groups ----
    #pragma unroll
    for (int k2 = 0; k2 < 4; ++k2) {
      const int ko = ((k2 * 2 + h) ^ sw) * 8;
      short8 pf = *(const short8*)&pwave[q * 64 + ko];
      #pragma unroll
      for (int dg = 0; dg < 4; ++dg) {
        short8 vf = *(const short8*)&Vc[(dg * 32 + q) * 64 + ko];
        O32[dg] = __builtin_amdgcn_mfma_f32_32x32x16_bf16(vf, pf, O32[dg], 0, 0, 0);
      }
    }
  }

  // ---- epilogue: lane holds out^T[d = dg*32+(r&3)+8*(r>>2)+4h][q] ----
  const int row = b * Sn + q0 + w * 32 + q;
  if constexpr (DIRECT) {
    const float inv = 1.0f / l_i;
    float* orow = outg + (size_t)row * Dn;
    #pragma unroll
    for (int dg = 0; dg < 4; ++dg)
      #pragma unroll
      for (int ro = 0; ro < 4; ++ro) {
        float4 f = make_float4(O32[dg][4 * ro] * inv,     O32[dg][4 * ro + 1] * inv,
                               O32[dg][4 * ro + 2] * inv, O32[dg][4 * ro + 3] * inv);
        *(float4*)&orow[dg * 32 + 8 * ro + 4 * h] = f;
      }
  } else {
    __half* orow = Op + ((size_t)s * ROWS + row) * Dn;
    #pragma unroll
    for (int dg = 0; dg < 4; ++dg)
      #pragma unroll
      for (int ro = 0; ro < 4; ++ro) {
        union { __half2 h2[2]; uint2 u; } pk;
        pk.h2[0] = __floats2half2_rn(O32[dg][4 * ro],     O32[dg][4 * ro + 1]);
        pk.h2[1] = __floats2half2_rn(O32[dg][4 * ro + 2], O32[dg][4 * ro + 3]);
        *(uint2*)&orow[dg * 32 + 8 * ro + 4 * h] = pk.u;
      }
    if (h == 0) {
      Mp[s * ROWS + row] = m_i;
      Lp[s * ROWS + row] = l_i;
    }
  }
}

// Merge NSPLIT fp16 partials (m in log2 domain): O = sum O_s*2^{m_s-m}; out = O/l.
__global__ __launch_bounds__(256)
void attn_combine(const __half* __restrict__ Op, const float* __restrict__ Mp,
                  const float* __restrict__ Lp, float4* __restrict__ out4) {
  const int gid = blockIdx.x * 256 + threadIdx.x;
  const int row = gid >> 5;
  const int c4  = gid & 31;
  float ms[NSPLIT];
  float m = -INFINITY;
  #pragma unroll
  for (int s = 0; s < NSPLIT; ++s) { ms[s] = Mp[s * ROWS + row]; m = fmaxf(m, ms[s]); }
  float l = 0.0f;
  float4 acc = make_float4(0.f, 0.f, 0.f, 0.f);
  #pragma unroll
  for (int s = 0; s < NSPLIT; ++s) {
    float wgt = EXP2(ms[s] - m);
    l = fmaf(Lp[s * ROWS + row], wgt, l);
    union { uint2 u; __half2 h2[2]; } pk;
    pk.u = ((const uint2*)Op)[(size_t)(s * ROWS + row) * 32 + c4];
    float2 f0 = __half22float2(pk.h2[0]);
    float2 f1 = __half22float2(pk.h2[1]);
    acc.x = fmaf(f0.x, wgt, acc.x);
    acc.y = fmaf(f0.y, wgt, acc.y);
    acc.z = fmaf(f1.x, wgt, acc.z);
    acc.w = fmaf(f1.y, wgt, acc.w);
  }
  float inv = 1.0f / l;
  out4[(size_t)row * 32 + c4] = make_float4(acc.x * inv, acc.y * inv, acc.z * inv, acc.w * inv);
}

extern "C" void kernel_launch(void* const* d_in, const int* in_sizes, int n_in,
                              void* d_out, int out_size, void* d_ws, size_t ws_size,
                              hipStream_t stream) {
  const float* q = (const float*)d_in[0];
  const float* k = (const float*)d_in[1];
  const float* v = (const float*)d_in[2];
  const unsigned char* m = (const unsigned char*)d_in[3];
  float* out = (float*)d_out;
  (void)in_sizes; (void)n_in; (void)out_size;

  constexpr size_t OPB = (size_t)NSPLIT * ROWS * Dn * sizeof(__half); // 16.8 MB
  constexpr size_t MLB = (size_t)NSPLIT * ROWS * sizeof(float);       // 256 KB
  constexpr size_t KPB = (size_t)Bn * NKB * TILE_USH * 2;             // 4 MB
  constexpr size_t MBB = (size_t)ROWS * sizeof(float);                // 64 KB

  char* ws = (char*)d_ws;
  if (ws_size >= OPB + 2 * MLB + 2 * KPB + MBB) {
    __half* Op = (__half*)ws;
    float* Mp = (float*)(ws + OPB);
    float* Lp = (float*)(ws + OPB + MLB);
    unsigned short* Kp = (unsigned short*)(ws + OPB + 2 * MLB);
    unsigned short* Vp = (unsigned short*)(ws + OPB + 2 * MLB + KPB);
    float* mb2 = (float*)(ws + OPB + 2 * MLB + 2 * KPB);
    prep<<<dim3(Bn * NKB * 4), dim3(256), 0, stream>>>(k, v, m, Kp, Vp, mb2);
    attn_fwd<NSPLIT, false><<<dim3(Bn * QTILES * NSPLIT), dim3(256), 0, stream>>>(
        q, Kp, Vp, mb2, out, Op, Mp, Lp);
    attn_combine<<<dim3(ROWS * 32 / 256), dim3(256), 0, stream>>>(
        Op, Mp, Lp, (float4*)out);
  } else if (ws_size >= 2 * KPB + MBB) {
    unsigned short* Kp = (unsigned short*)ws;
    unsigned short* Vp = (unsigned short*)(ws + KPB);
    float* mb2 = (float*)(ws + 2 * KPB);
    prep<<<dim3(Bn * NKB * 4), dim3(256), 0, stream>>>(k, v, m, Kp, Vp, mb2);
    attn_fwd<1, true><<<dim3(Bn * QTILES), dim3(256), 0, stream>>>(
        q, Kp, Vp, mb2, out, nullptr, nullptr, nullptr);
  }
}